// Round 5
// baseline (468.875 us; speedup 1.0000x reference)
//
#include <hip/hip_runtime.h>
#include <hip/hip_bf16.h>

// Problem constants
#define B_ 8
#define C_ 64
#define H_ 240
#define W_ 320
#define HW_ (H_ * W_)      // 76800
#define HW4_ (HW_ / 4)     // 19200
#define K_ 10
#define ALPHA_ 0.02f
#define DELTA_ 0.5f
#define MIN_WEIGHT_ 50.0f

#define NBLK 1024          // 4 blocks/CU x 256 CUs: all co-resident by launch_bounds
#define SCOPE_AGENT __HIP_MEMORY_SCOPE_AGENT

// Workspace layout (floats):
//   [0, 5120)      sums[b*64+c][k]
//   [5120, 5200)   counts[b*10+k]
//   [5200, 10320)  means[b*64+c][k]
//   [10320, 10400) S2[b*10+k]
//   [10400, 10480) Nk[b*10+k]
//   [10480]        indicator total
//   [10488]        barrier 1 (uint)
//   [10489]        barrier 2 (uint)

__device__ inline float wave_red(float v) {
#pragma unroll
  for (int off = 32; off > 0; off >>= 1) v += __shfl_down(v, off, 64);
  return v;
}

__device__ inline void grid_barrier(unsigned* bar, int tid, bool wait) {
  __syncthreads();  // drains vmcnt: all this block's atomics are globally visible
  if (tid == 0) {
    __hip_atomic_fetch_add(bar, 1u, __ATOMIC_ACQ_REL, SCOPE_AGENT);
    if (wait) {
      while (__hip_atomic_load(bar, __ATOMIC_ACQUIRE, SCOPE_AGENT) < NBLK)
        __builtin_amdgcn_s_sleep(8);
    }
  }
  __syncthreads();
}

__device__ inline float aload(const float* p) {
  return __hip_atomic_load(p, __ATOMIC_RELAXED, SCOPE_AGENT);
}

// ---------------------------------------------------------------------------
// One kernel, manual grid barriers (capture-safe; co-residency guaranteed by
// __launch_bounds__(256,4) and NBLK == 4*256).
// Phase A: masked per-(b,c,k) sums + per-(b,k) counts   (x from HBM)
// Phase BC: per-block means normalization + intra pass  (x L3-hot)
// Phase D: block 0 — inter hinge + finalize
// ---------------------------------------------------------------------------
__global__ __launch_bounds__(256, 4) void fused(
    const float* __restrict__ x, const int* __restrict__ cm,
    float* __restrict__ ws, float* __restrict__ out) {
  float* sums = ws;                 // 5120
  float* counts = ws + 5120;        // 80
  float* means = ws + 5200;         // 5120
  float* S2 = ws + 10320;           // 80
  float* Nk = ws + 10400;           // 80
  float* indtot = ws + 10480;       // 1
  unsigned* bar1 = (unsigned*)(ws + 10488);
  unsigned* bar2 = (unsigned*)(ws + 10489);

  const int blk = blockIdx.x;
  const int tid = threadIdx.x;

  __shared__ float mlds[C_ * K_];   // 2.5 KB, [c*10+k]
  __shared__ float cl[K_];
  __shared__ float nrm[K_];
  __shared__ float4 pd[256];        // 4 KB
  __shared__ float s2b[K_];
  __shared__ float nkb[K_];
  __shared__ float red[256];        // 1 KB
  __shared__ float mall[B_ * C_ * K_];  // 20 KB (phase D, block 0 only)

  // ---------------- Phase A: sums + counts ----------------
  {
    const int plane = blk >> 1;        // b*64+c
    const int half = blk & 1;
    const int b = plane >> 6;
    const int c = plane & 63;
    const float4* __restrict__ xp = (const float4*)(x + (size_t)plane * HW_);
    const int4* __restrict__ cp = (const int4*)(cm + (size_t)b * HW_);

    float acc[K_];
#pragma unroll
    for (int j = 0; j < K_; ++j) acc[j] = 0.f;
    float cnt[K_];
#pragma unroll
    for (int j = 0; j < K_; ++j) cnt[j] = 0.f;
    const bool do_cnt = (c == 0);

    const int lo = half * (HW4_ / 2);
    const int hi = lo + (HW4_ / 2);
#pragma unroll 2
    for (int i = lo + tid; i < hi; i += 256) {
      float4 v = xp[i];
      int4 k4 = cp[i];
#pragma unroll
      for (int j = 0; j < K_; ++j) {
        acc[j] += (k4.x == j ? v.x : 0.f);
        acc[j] += (k4.y == j ? v.y : 0.f);
        acc[j] += (k4.z == j ? v.z : 0.f);
        acc[j] += (k4.w == j ? v.w : 0.f);
      }
      if (do_cnt) {
#pragma unroll
        for (int j = 0; j < K_; ++j) {
          cnt[j] += (float)((k4.x == j) + (k4.y == j) + (k4.z == j) + (k4.w == j));
        }
      }
    }

#pragma unroll
    for (int j = 0; j < K_; ++j) {
      float v = wave_red(acc[j]);
      if ((tid & 63) == 0) atomicAdd(&sums[plane * K_ + j], v);
    }
    if (do_cnt) {
#pragma unroll
      for (int j = 0; j < K_; ++j) {
        float v = wave_red(cnt[j]);
        if ((tid & 63) == 0) atomicAdd(&counts[b * K_ + j], v);
      }
    }
  }

  grid_barrier(bar1, tid, true);

  // ---------------- Phase BC: means normalization + intra ----------------
  {
    const int b = blk >> 7;            // 8 batches x 128 chunks
    const int chunk = blk & 127;

    if (tid < K_) {
      cl[tid] = aload(&counts[b * K_ + tid]);
      s2b[tid] = 0.f;
      nkb[tid] = 0.f;
    }
    __syncthreads();
    for (int i = tid; i < C_ * K_; i += 256)
      mlds[i] = aload(&sums[b * C_ * K_ + i]) / (cl[i % K_] + 1e-10f);
    __syncthreads();
    if (tid < K_) {
      float n2 = 0.f;
#pragma unroll
      for (int c = 0; c < C_; ++c) {
        const float mm = mlds[c * K_ + tid];
        n2 += mm * mm;
      }
      nrm[tid] = 1.f / fmaxf(sqrtf(n2), 1e-12f);
    }
    __syncthreads();
    for (int i = tid; i < C_ * K_; i += 256) mlds[i] *= nrm[i % K_];
    __syncthreads();
    if (chunk == 0) {  // publish normalized means for phase D
      for (int i = tid; i < C_ * K_; i += 256)
        __hip_atomic_store(&means[b * C_ * K_ + i], mlds[i], __ATOMIC_RELAXED,
                           SCOPE_AGENT);
    }

    // intra: 150 float4-pixels per chunk, 64 pixel-lanes x 4 channel-groups
    const int lane_p = tid & 63;
    const int grp = tid >> 6;
    const int lo = chunk * (HW4_ / 128);  // 150 per chunk
    const float4* __restrict__ xb = (const float4*)(x + (size_t)b * C_ * HW_);
    const int4* __restrict__ cp = (const int4*)(cm + (size_t)b * HW_);

    for (int base = 0; base < HW4_ / 128; base += 64) {
      const int off = base + lane_p;
      const bool act = off < HW4_ / 128;
      const int p4 = lo + off;
      int4 k4 = act ? cp[p4] : make_int4(0, 0, 0, 0);
      float d0 = 0.f, d1 = 0.f, d2 = 0.f, d3 = 0.f;
      if (act) {
        const int c0 = grp * (C_ / 4);
#pragma unroll
        for (int cc = 0; cc < C_ / 4; ++cc) {
          const int c = c0 + cc;
          float4 v = xb[c * HW4_ + p4];
          const float* mr = &mlds[c * K_];
          d0 += v.x * mr[k4.x];
          d1 += v.y * mr[k4.y];
          d2 += v.z * mr[k4.z];
          d3 += v.w * mr[k4.w];
        }
      }
      pd[tid] = make_float4(d0, d1, d2, d3);
      __syncthreads();
      if (grp == 0 && act) {
        float4 a = pd[lane_p];
        float4 bb = pd[lane_p + 64];
        float4 cc = pd[lane_p + 128];
        float4 dd = pd[lane_p + 192];
        const float i0 = 0.5f * (1.f - (a.x + bb.x + cc.x + dd.x));
        const float i1 = 0.5f * (1.f - (a.y + bb.y + cc.y + dd.y));
        const float i2 = 0.5f * (1.f - (a.z + bb.z + cc.z + dd.z));
        const float i3 = 0.5f * (1.f - (a.w + bb.w + cc.w + dd.w));
        atomicAdd(&s2b[k4.x], i0 * i0);
        atomicAdd(&s2b[k4.y], i1 * i1);
        atomicAdd(&s2b[k4.z], i2 * i2);
        atomicAdd(&s2b[k4.w], i3 * i3);
        atomicAdd(&nkb[k4.x], i0 > ALPHA_ ? 1.f : 0.f);
        atomicAdd(&nkb[k4.y], i1 > ALPHA_ ? 1.f : 0.f);
        atomicAdd(&nkb[k4.z], i2 > ALPHA_ ? 1.f : 0.f);
        atomicAdd(&nkb[k4.w], i3 > ALPHA_ ? 1.f : 0.f);
      }
      __syncthreads();
    }

    if (tid < K_) {
      atomicAdd(&S2[b * K_ + tid], s2b[tid]);
      atomicAdd(&Nk[b * K_ + tid], nkb[tid]);
      atomicAdd(indtot, nkb[tid]);
    }
  }

  // last barrier: non-zero blocks just arrive and exit; block 0 waits
  grid_barrier(bar2, tid, blk == 0);
  if (blk != 0) return;

  // ---------------- Phase D: inter + finalize (block 0) ----------------
  for (int i = tid; i < B_ * C_ * K_; i += 256) mall[i] = aload(&means[i]);
  __syncthreads();

  float h2 = 0.f;
  for (int t = tid; t < B_ * 45; t += 256) {
    const int b = t / 45;
    int idx = t % 45;
    int k = 0, l = 0;
    for (k = 0; k < K_; ++k) {
      const int row = K_ - 1 - k;
      if (idx < row) { l = k + 1 + idx; break; }
      idx -= row;
    }
    float g = 0.f;
#pragma unroll 8
    for (int c = 0; c < C_; ++c)
      g += mall[(b * C_ + c) * K_ + k] * mall[(b * C_ + c) * K_ + l];
    const float inter_d = 0.5f * (1.f - g);
    const float h = fmaxf(DELTA_ - inter_d, 0.f);
    h2 += 2.f * h * h;  // (k,l) and (l,k)
  }
  red[tid] = h2;
  __syncthreads();
  for (int s = 128; s > 0; s >>= 1) {
    if (tid < s) red[tid] += red[tid + s];
    __syncthreads();
  }
  const float inter = red[0] / (float)((K_ * (K_ - 1) / 2) * B_);
  __syncthreads();

  float iv = 0.f;
  if (tid < B_ * K_) {
    const float s2 = aload(&S2[tid]);
    const float nk = aload(&Nk[tid]);
    iv = s2 / (fmaxf(nk, MIN_WEIGHT_) * (float)K_);
  }
  red[tid] = iv;
  __syncthreads();
  for (int s = 128; s > 0; s >>= 1) {
    if (tid < s) red[tid] += red[tid + s];
    __syncthreads();
  }
  if (tid == 0) {
    float intra = red[0] / (float)B_;
    if (!(aload(indtot) > 0.f)) intra = 0.f;
    out[0] = intra + inter;
    out[1] = intra;
    out[2] = inter;
  }
}

extern "C" void kernel_launch(void* const* d_in, const int* in_sizes, int n_in,
                              void* d_out, int out_size, void* d_ws, size_t ws_size,
                              hipStream_t stream) {
  const float* x = (const float*)d_in[0];
  const int* cm = (const int*)d_in[1];
  float* ws = (float*)d_ws;

  // ws is re-poisoned to 0xAA before every call — zero accumulators AND the
  // grid-barrier counters (indices 10488/10489).
  hipMemsetAsync(d_ws, 0, 10496 * sizeof(float), stream);

  fused<<<NBLK, 256, 0, stream>>>(x, cm, ws, (float*)d_out);
}

// Round 6
// 304.450 us; speedup vs baseline: 1.5401x; 1.5401x over previous
//
#include <hip/hip_runtime.h>
#include <hip/hip_bf16.h>

// Problem constants
#define B_ 8
#define C_ 64
#define H_ 240
#define W_ 320
#define HW_ (H_ * W_)      // 76800
#define HW4_ (HW_ / 4)     // 19200
#define K_ 10
#define ALPHA_ 0.02f
#define DELTA_ 0.5f
#define MIN_WEIGHT_ 50.0f

#define K1_Z 15            // 19200/15 = 1280 float4/block; /256 thr = 5 iters exact

// Workspace layout (floats):
//   [0, 5120)      sums[b*64+c][k]
//   [5120, 5200)   counts[b*10+k]
//   [5200, 10320)  means[b*64+c][k] (normalized, written by k3 chunk-0 blocks)
//   [10320, 10400) S2[b*10+k]
//   [10400, 10480) Nk[b*10+k]
//   [10480]        indicator total

// ---------------------------------------------------------------------------
// Kernel 1: masked channel sums + cluster counts.
// grid (64, 8, 15), block 256. Each thread: exactly 5 float4+int4 loads,
// ALL issued before any consumption (5 outstanding vmem/wave -> latency hid).
// ---------------------------------------------------------------------------
__global__ __launch_bounds__(256) void k1_sums(
    const float* __restrict__ x, const int* __restrict__ cm,
    float* __restrict__ sums, float* __restrict__ counts) {
  const int c = blockIdx.x;
  const int b = blockIdx.y;
  const int z = blockIdx.z;
  const int tid = threadIdx.x;

  const int lo = z * (HW4_ / K1_Z);  // 1280 float4 per slice

  const float4* __restrict__ xp =
      (const float4*)(x + (size_t)(b * C_ + c) * HW_);
  const int4* __restrict__ cp = (const int4*)(cm + (size_t)b * HW_);

  // ---- batched loads: 5 x (float4 + int4), all in flight at once ----
  float4 v[5];
  int4 kk[5];
#pragma unroll
  for (int u = 0; u < 5; ++u) {
    const int i = lo + u * 256 + tid;
    v[u] = xp[i];
    kk[u] = cp[i];
  }

  float acc[K_];
#pragma unroll
  for (int j = 0; j < K_; ++j) acc[j] = 0.f;

#pragma unroll
  for (int u = 0; u < 5; ++u) {
#pragma unroll
    for (int j = 0; j < K_; ++j) {
      acc[j] += (kk[u].x == j ? v[u].x : 0.f);
      acc[j] += (kk[u].y == j ? v[u].y : 0.f);
      acc[j] += (kk[u].z == j ? v[u].z : 0.f);
      acc[j] += (kk[u].w == j ? v[u].w : 0.f);
    }
  }

  // wave-level reduce (wave = 64), one atomic per wave per bin
#pragma unroll
  for (int j = 0; j < K_; ++j) {
    float s = acc[j];
#pragma unroll
    for (int off = 32; off > 0; off >>= 1) s += __shfl_down(s, off, 64);
    if ((tid & 63) == 0) atomicAdd(&sums[(b * C_ + c) * K_ + j], s);
  }

  // counts: only the 120 c==0 blocks (amortized ~1/64 of VALU)
  if (c == 0) {
    float cnt[K_];
#pragma unroll
    for (int j = 0; j < K_; ++j) cnt[j] = 0.f;
#pragma unroll
    for (int u = 0; u < 5; ++u) {
#pragma unroll
      for (int j = 0; j < K_; ++j) {
        cnt[j] += (float)((kk[u].x == j) + (kk[u].y == j) + (kk[u].z == j) +
                          (kk[u].w == j));
      }
    }
#pragma unroll
    for (int j = 0; j < K_; ++j) {
      float s = cnt[j];
#pragma unroll
      for (int off = 32; off > 0; off >>= 1) s += __shfl_down(s, off, 64);
      if ((tid & 63) == 0) atomicAdd(&counts[b * K_ + j], s);
    }
  }
}

// ---------------------------------------------------------------------------
// Kernel 3: per-block means normalization (from sums/counts, no k2 bubble)
// + per-pixel intra distance -> S2/Nk per cluster.
// grid (300, 8), block 256 = 64 pixel-lanes x 4 channel-groups.
// All 16 x-loads per thread batched into registers before the LDS/FMA pass.
// ---------------------------------------------------------------------------
__global__ __launch_bounds__(256, 4) void k3_intra(
    const float* __restrict__ x, const int* __restrict__ cm,
    const float* __restrict__ sums, const float* __restrict__ counts,
    float* __restrict__ means, float* __restrict__ S2,
    float* __restrict__ Nk, float* __restrict__ indtot) {
  const int b = blockIdx.y;
  const int chunk = blockIdx.x;
  const int tid = threadIdx.x;
  const int lane_p = tid & 63;   // pixel-unit lane (one float4 = 4 pixels)
  const int grp = tid >> 6;      // channel group 0..3

  __shared__ float mlds[C_ * K_];   // 640 floats, [c*10+k]
  __shared__ float nrm[K_];
  __shared__ float4 pd[256];
  __shared__ float s2b[K_];
  __shared__ float nkb[K_];

  // ---- issue this thread's global loads FIRST (16 float4 + cm, in flight
  //      while the means preamble runs) ----
  const int p4 = chunk * 64 + lane_p;  // 0..19199
  const int c0 = grp * (C_ / 4);
  const float4* __restrict__ xb = (const float4*)(x + (size_t)b * C_ * HW_);
  const int4 k4 = ((const int4*)(cm + (size_t)b * HW_))[p4];
  float4 v[16];
#pragma unroll
  for (int cc = 0; cc < C_ / 4; ++cc) v[cc] = xb[(c0 + cc) * HW4_ + p4];

  // ---- local means normalization (replaces k2) ----
  for (int i = tid; i < C_ * K_; i += 256) {
    const int k = i % K_;
    mlds[i] = sums[b * C_ * K_ + i] / (counts[b * K_ + k] + 1e-10f);
  }
  if (tid < K_) { s2b[tid] = 0.f; nkb[tid] = 0.f; }
  __syncthreads();
  if (tid < K_) {
    float n2 = 0.f;
#pragma unroll
    for (int c = 0; c < C_; ++c) {
      const float mm = mlds[c * K_ + tid];
      n2 += mm * mm;
    }
    nrm[tid] = 1.f / fmaxf(sqrtf(n2), 1e-12f);
  }
  __syncthreads();
  for (int i = tid; i < C_ * K_; i += 256) mlds[i] *= nrm[i % K_];
  __syncthreads();
  if (chunk == 0) {  // publish normalized means for k4
    for (int i = tid; i < C_ * K_; i += 256) means[b * C_ * K_ + i] = mlds[i];
  }

  // ---- intra distances: consume the 16 registers ----
  float d0 = 0.f, d1 = 0.f, d2 = 0.f, d3 = 0.f;
#pragma unroll
  for (int cc = 0; cc < C_ / 4; ++cc) {
    const float* mr = &mlds[(c0 + cc) * K_];
    d0 += v[cc].x * mr[k4.x];
    d1 += v[cc].y * mr[k4.y];
    d2 += v[cc].z * mr[k4.z];
    d3 += v[cc].w * mr[k4.w];
  }
  pd[tid] = make_float4(d0, d1, d2, d3);
  __syncthreads();

  if (grp == 0) {
    float4 a = pd[lane_p];
    float4 bb = pd[lane_p + 64];
    float4 cc = pd[lane_p + 128];
    float4 dd = pd[lane_p + 192];
    const float i0 = 0.5f * (1.f - (a.x + bb.x + cc.x + dd.x));
    const float i1 = 0.5f * (1.f - (a.y + bb.y + cc.y + dd.y));
    const float i2 = 0.5f * (1.f - (a.z + bb.z + cc.z + dd.z));
    const float i3 = 0.5f * (1.f - (a.w + bb.w + cc.w + dd.w));

    atomicAdd(&s2b[k4.x], i0 * i0);
    atomicAdd(&s2b[k4.y], i1 * i1);
    atomicAdd(&s2b[k4.z], i2 * i2);
    atomicAdd(&s2b[k4.w], i3 * i3);
    atomicAdd(&nkb[k4.x], i0 > ALPHA_ ? 1.f : 0.f);
    atomicAdd(&nkb[k4.y], i1 > ALPHA_ ? 1.f : 0.f);
    atomicAdd(&nkb[k4.z], i2 > ALPHA_ ? 1.f : 0.f);
    atomicAdd(&nkb[k4.w], i3 > ALPHA_ ? 1.f : 0.f);
  }
  __syncthreads();

  if (tid < K_) {
    atomicAdd(&S2[b * K_ + tid], s2b[tid]);
    atomicAdd(&Nk[b * K_ + tid], nkb[tid]);
    atomicAdd(indtot, nkb[tid]);
  }
}

// ---------------------------------------------------------------------------
// Kernel 4: inter hinge loss + finalize. One block.
// ---------------------------------------------------------------------------
__global__ __launch_bounds__(256) void k4_final(
    const float* __restrict__ means, const float* __restrict__ S2,
    const float* __restrict__ Nk, const float* __restrict__ indtot,
    float* __restrict__ out) {
  const int tid = threadIdx.x;

  float h2 = 0.f;
  for (int t = tid; t < B_ * 45; t += 256) {
    const int b = t / 45;
    int idx = t % 45;
    int k = 0, l = 0;
    for (k = 0; k < K_; ++k) {
      const int row = K_ - 1 - k;
      if (idx < row) { l = k + 1 + idx; break; }
      idx -= row;
    }
    float g = 0.f;
    for (int c = 0; c < C_; ++c)
      g += means[(b * C_ + c) * K_ + k] * means[(b * C_ + c) * K_ + l];
    const float inter_d = 0.5f * (1.f - g);
    const float h = fmaxf(DELTA_ - inter_d, 0.f);
    h2 += 2.f * h * h;  // (k,l) and (l,k)
  }

  __shared__ float red[256];
  red[tid] = h2;
  __syncthreads();
  for (int s = 128; s > 0; s >>= 1) {
    if (tid < s) red[tid] += red[tid + s];
    __syncthreads();
  }
  if (tid == 0) {
    const float inter = red[0] / (float)((K_ * (K_ - 1) / 2) * B_);
    float intra = 0.f;
    for (int i = 0; i < B_ * K_; ++i) {
      const float w = fmaxf(Nk[i], MIN_WEIGHT_) * (float)K_;
      intra += S2[i] / w;
    }
    intra /= (float)B_;
    if (!(indtot[0] > 0.f)) intra = 0.f;
    out[0] = intra + inter;
    out[1] = intra;
    out[2] = inter;
  }
}

extern "C" void kernel_launch(void* const* d_in, const int* in_sizes, int n_in,
                              void* d_out, int out_size, void* d_ws, size_t ws_size,
                              hipStream_t stream) {
  const float* x = (const float*)d_in[0];
  const int* cm = (const int*)d_in[1];

  float* ws = (float*)d_ws;
  float* sums = ws;             // 5120
  float* counts = ws + 5120;    // 80
  float* means = ws + 5200;     // 5120
  float* S2 = ws + 10320;       // 80
  float* Nk = ws + 10400;       // 80
  float* indtot = ws + 10480;   // 1

  // ws is re-poisoned to 0xAA before every call — zero the accumulators.
  hipMemsetAsync(d_ws, 0, 10481 * sizeof(float), stream);

  k1_sums<<<dim3(C_, B_, K1_Z), 256, 0, stream>>>(x, cm, sums, counts);
  k3_intra<<<dim3(HW4_ / 64, B_), 256, 0, stream>>>(x, cm, sums, counts, means,
                                                    S2, Nk, indtot);
  k4_final<<<1, 256, 0, stream>>>(means, S2, Nk, indtot, (float*)d_out);
}

// Round 7
// 303.036 us; speedup vs baseline: 1.5473x; 1.0047x over previous
//
#include <hip/hip_runtime.h>
#include <hip/hip_bf16.h>

// Problem constants
#define B_ 8
#define C_ 64
#define H_ 240
#define W_ 320
#define HW_ (H_ * W_)      // 76800
#define HW4_ (HW_ / 4)     // 19200
#define K_ 10
#define ALPHA_ 0.02f
#define DELTA_ 0.5f
#define MIN_WEIGHT_ 50.0f

#define K1_Z 5             // 19200/5 = 3840 float4/block; /256 thr = 15 iters exact

// Workspace layout (floats):
//   [0, 5120)      sums[b*64+c][k]
//   [5120, 5200)   counts[b*10+k]
//   [5200, 10320)  means[b*64+c][k] (normalized, written by k3 chunk-0 blocks)
//   [10320, 10400) S2[b*10+k]
//   [10400, 10480) Nk[b*10+k]
//   [10480]        indicator total

// ---------------------------------------------------------------------------
// Kernel 1: masked channel sums + cluster counts.
// grid (64, 8, 5), block 256. 15 streaming iterations per thread (long blocks
// amortize the reduction tail; unroll 3 gives ~6 outstanding loads).
// 4 waves combine in LDS -> 10 global atomics per block (not per wave).
// ---------------------------------------------------------------------------
__global__ __launch_bounds__(256) void k1_sums(
    const float* __restrict__ x, const int* __restrict__ cm,
    float* __restrict__ sums, float* __restrict__ counts) {
  const int c = blockIdx.x;
  const int b = blockIdx.y;
  const int z = blockIdx.z;
  const int tid = threadIdx.x;
  const int wave = tid >> 6;

  const int lo = z * (HW4_ / K1_Z);   // 3840 float4 per slice
  const int hi = lo + (HW4_ / K1_Z);

  const float4* __restrict__ xp =
      (const float4*)(x + (size_t)(b * C_ + c) * HW_);
  const int4* __restrict__ cp = (const int4*)(cm + (size_t)b * HW_);

  __shared__ float wacc[4][K_];
  __shared__ float wcnt[4][K_];

  float acc[K_];
#pragma unroll
  for (int j = 0; j < K_; ++j) acc[j] = 0.f;
  float cnt[K_];
#pragma unroll
  for (int j = 0; j < K_; ++j) cnt[j] = 0.f;
  const bool do_cnt = (c == 0);

#pragma unroll 3
  for (int i = lo + tid; i < hi; i += 256) {
    float4 v = xp[i];
    int4 k4 = cp[i];
#pragma unroll
    for (int j = 0; j < K_; ++j) {
      acc[j] += (k4.x == j ? v.x : 0.f);
      acc[j] += (k4.y == j ? v.y : 0.f);
      acc[j] += (k4.z == j ? v.z : 0.f);
      acc[j] += (k4.w == j ? v.w : 0.f);
    }
    if (do_cnt) {
#pragma unroll
      for (int j = 0; j < K_; ++j) {
        cnt[j] += (float)((k4.x == j) + (k4.y == j) + (k4.z == j) + (k4.w == j));
      }
    }
  }

  // wave-level shuffle reduce; lane 0 stages wave totals in LDS
#pragma unroll
  for (int j = 0; j < K_; ++j) {
    float s = acc[j];
#pragma unroll
    for (int off = 32; off > 0; off >>= 1) s += __shfl_down(s, off, 64);
    if ((tid & 63) == 0) wacc[wave][j] = s;
  }
  if (do_cnt) {
#pragma unroll
    for (int j = 0; j < K_; ++j) {
      float s = cnt[j];
#pragma unroll
      for (int off = 32; off > 0; off >>= 1) s += __shfl_down(s, off, 64);
      if ((tid & 63) == 0) wcnt[wave][j] = s;
    }
  }
  __syncthreads();

  // one global atomic per bin per block
  if (tid < K_) {
    const float s = wacc[0][tid] + wacc[1][tid] + wacc[2][tid] + wacc[3][tid];
    atomicAdd(&sums[(b * C_ + c) * K_ + tid], s);
    if (do_cnt) {
      const float s2 = wcnt[0][tid] + wcnt[1][tid] + wcnt[2][tid] + wcnt[3][tid];
      atomicAdd(&counts[b * K_ + tid], s2);
    }
  }
}

// ---------------------------------------------------------------------------
// Kernel 3: per-block means normalization (from sums/counts, no k2 bubble)
// + per-pixel intra distance -> S2/Nk per cluster.
// grid (300, 8), block 256 = 64 pixel-lanes x 4 channel-groups.
// All 16 x-loads per thread batched into registers before the LDS/FMA pass.
// ---------------------------------------------------------------------------
__global__ __launch_bounds__(256, 4) void k3_intra(
    const float* __restrict__ x, const int* __restrict__ cm,
    const float* __restrict__ sums, const float* __restrict__ counts,
    float* __restrict__ means, float* __restrict__ S2,
    float* __restrict__ Nk, float* __restrict__ indtot) {
  const int b = blockIdx.y;
  const int chunk = blockIdx.x;
  const int tid = threadIdx.x;
  const int lane_p = tid & 63;   // pixel-unit lane (one float4 = 4 pixels)
  const int grp = tid >> 6;      // channel group 0..3

  __shared__ float mlds[C_ * K_];   // 640 floats, [c*10+k]
  __shared__ float nrm[K_];
  __shared__ float4 pd[256];
  __shared__ float s2b[K_];
  __shared__ float nkb[K_];

  // ---- issue this thread's global loads FIRST (16 float4 + cm, in flight
  //      while the means preamble runs) ----
  const int p4 = chunk * 64 + lane_p;  // 0..19199
  const int c0 = grp * (C_ / 4);
  const float4* __restrict__ xb = (const float4*)(x + (size_t)b * C_ * HW_);
  const int4 k4 = ((const int4*)(cm + (size_t)b * HW_))[p4];
  float4 v[16];
#pragma unroll
  for (int cc = 0; cc < C_ / 4; ++cc) v[cc] = xb[(c0 + cc) * HW4_ + p4];

  // ---- local means normalization (replaces k2) ----
  for (int i = tid; i < C_ * K_; i += 256) {
    const int k = i % K_;
    mlds[i] = sums[b * C_ * K_ + i] / (counts[b * K_ + k] + 1e-10f);
  }
  if (tid < K_) { s2b[tid] = 0.f; nkb[tid] = 0.f; }
  __syncthreads();
  if (tid < K_) {
    float n2 = 0.f;
#pragma unroll
    for (int c = 0; c < C_; ++c) {
      const float mm = mlds[c * K_ + tid];
      n2 += mm * mm;
    }
    nrm[tid] = 1.f / fmaxf(sqrtf(n2), 1e-12f);
  }
  __syncthreads();
  for (int i = tid; i < C_ * K_; i += 256) mlds[i] *= nrm[i % K_];
  __syncthreads();
  if (chunk == 0) {  // publish normalized means for k4
    for (int i = tid; i < C_ * K_; i += 256) means[b * C_ * K_ + i] = mlds[i];
  }

  // ---- intra distances: consume the 16 registers ----
  float d0 = 0.f, d1 = 0.f, d2 = 0.f, d3 = 0.f;
#pragma unroll
  for (int cc = 0; cc < C_ / 4; ++cc) {
    const float* mr = &mlds[(c0 + cc) * K_];
    d0 += v[cc].x * mr[k4.x];
    d1 += v[cc].y * mr[k4.y];
    d2 += v[cc].z * mr[k4.z];
    d3 += v[cc].w * mr[k4.w];
  }
  pd[tid] = make_float4(d0, d1, d2, d3);
  __syncthreads();

  if (grp == 0) {
    float4 a = pd[lane_p];
    float4 bb = pd[lane_p + 64];
    float4 cc = pd[lane_p + 128];
    float4 dd = pd[lane_p + 192];
    const float i0 = 0.5f * (1.f - (a.x + bb.x + cc.x + dd.x));
    const float i1 = 0.5f * (1.f - (a.y + bb.y + cc.y + dd.y));
    const float i2 = 0.5f * (1.f - (a.z + bb.z + cc.z + dd.z));
    const float i3 = 0.5f * (1.f - (a.w + bb.w + cc.w + dd.w));

    atomicAdd(&s2b[k4.x], i0 * i0);
    atomicAdd(&s2b[k4.y], i1 * i1);
    atomicAdd(&s2b[k4.z], i2 * i2);
    atomicAdd(&s2b[k4.w], i3 * i3);
    atomicAdd(&nkb[k4.x], i0 > ALPHA_ ? 1.f : 0.f);
    atomicAdd(&nkb[k4.y], i1 > ALPHA_ ? 1.f : 0.f);
    atomicAdd(&nkb[k4.z], i2 > ALPHA_ ? 1.f : 0.f);
    atomicAdd(&nkb[k4.w], i3 > ALPHA_ ? 1.f : 0.f);
  }
  __syncthreads();

  if (tid < K_) {
    atomicAdd(&S2[b * K_ + tid], s2b[tid]);
    atomicAdd(&Nk[b * K_ + tid], nkb[tid]);
    atomicAdd(indtot, nkb[tid]);
  }
}

// ---------------------------------------------------------------------------
// Kernel 4: inter hinge loss + finalize. One block.
// ---------------------------------------------------------------------------
__global__ __launch_bounds__(256) void k4_final(
    const float* __restrict__ means, const float* __restrict__ S2,
    const float* __restrict__ Nk, const float* __restrict__ indtot,
    float* __restrict__ out) {
  const int tid = threadIdx.x;

  float h2 = 0.f;
  for (int t = tid; t < B_ * 45; t += 256) {
    const int b = t / 45;
    int idx = t % 45;
    int k = 0, l = 0;
    for (k = 0; k < K_; ++k) {
      const int row = K_ - 1 - k;
      if (idx < row) { l = k + 1 + idx; break; }
      idx -= row;
    }
    float g = 0.f;
    for (int c = 0; c < C_; ++c)
      g += means[(b * C_ + c) * K_ + k] * means[(b * C_ + c) * K_ + l];
    const float inter_d = 0.5f * (1.f - g);
    const float h = fmaxf(DELTA_ - inter_d, 0.f);
    h2 += 2.f * h * h;  // (k,l) and (l,k)
  }

  __shared__ float red[256];
  red[tid] = h2;
  __syncthreads();
  for (int s = 128; s > 0; s >>= 1) {
    if (tid < s) red[tid] += red[tid + s];
    __syncthreads();
  }
  if (tid == 0) {
    const float inter = red[0] / (float)((K_ * (K_ - 1) / 2) * B_);
    float intra = 0.f;
    for (int i = 0; i < B_ * K_; ++i) {
      const float w = fmaxf(Nk[i], MIN_WEIGHT_) * (float)K_;
      intra += S2[i] / w;
    }
    intra /= (float)B_;
    if (!(indtot[0] > 0.f)) intra = 0.f;
    out[0] = intra + inter;
    out[1] = intra;
    out[2] = inter;
  }
}

extern "C" void kernel_launch(void* const* d_in, const int* in_sizes, int n_in,
                              void* d_out, int out_size, void* d_ws, size_t ws_size,
                              hipStream_t stream) {
  const float* x = (const float*)d_in[0];
  const int* cm = (const int*)d_in[1];

  float* ws = (float*)d_ws;
  float* sums = ws;             // 5120
  float* counts = ws + 5120;    // 80
  float* means = ws + 5200;     // 5120
  float* S2 = ws + 10320;       // 80
  float* Nk = ws + 10400;       // 80
  float* indtot = ws + 10480;   // 1

  // ws is re-poisoned to 0xAA before every call — zero the accumulators.
  hipMemsetAsync(d_ws, 0, 10481 * sizeof(float), stream);

  k1_sums<<<dim3(C_, B_, K1_Z), 256, 0, stream>>>(x, cm, sums, counts);
  k3_intra<<<dim3(HW4_ / 64, B_), 256, 0, stream>>>(x, cm, sums, counts, means,
                                                    S2, Nk, indtot);
  k4_final<<<1, 256, 0, stream>>>(means, S2, Nk, indtot, (float*)d_out);
}